// Round 4
// baseline (5799.909 us; speedup 1.0000x reference)
//
#include <hip/hip_runtime.h>
#include <cstdint>
#include <cstddef>

#define B_  64
#define T_  512
#define I_  512
#define H_  1024

typedef float  f32x4  __attribute__((ext_vector_type(4)));
typedef __bf16 bf16x8 __attribute__((ext_vector_type(8)));
typedef unsigned short us4v __attribute__((ext_vector_type(4)));
typedef unsigned long long u64x2 __attribute__((ext_vector_type(2)));
typedef unsigned long long ull;

__device__ __forceinline__ unsigned short f2bf(float f) {
  unsigned int u = __float_as_uint(f);
  u = (u + 0x7fffu + ((u >> 16) & 1u)) >> 16;   // round-to-nearest-even
  return (unsigned short)u;
}

__device__ __forceinline__ float fast_tanh(float x) {
  x = fminf(10.f, fmaxf(-10.f, x));
  float e = __expf(2.f * x);
  return (e - 1.f) * __builtin_amdgcn_rcpf(e + 1.f);
}

// Relaxed agent-scope atomics: coherent through L3, NO cache-maintenance ops.
__device__ __forceinline__ void st_ag64(ull* p, ull v) {
  __hip_atomic_store(p, v, __ATOMIC_RELAXED, __HIP_MEMORY_SCOPE_AGENT);
}
__device__ __forceinline__ ull ld_ag64(const ull* p) {
  return __hip_atomic_load(p, __ATOMIC_RELAXED, __HIP_MEMORY_SCOPE_AGENT);
}
__device__ __forceinline__ void st_ag32(unsigned int* p, unsigned int v) {
  __hip_atomic_store(p, v, __ATOMIC_RELAXED, __HIP_MEMORY_SCOPE_AGENT);
}
__device__ __forceinline__ unsigned int ld_ag32(const unsigned int* p) {
  return __hip_atomic_load(p, __ATOMIC_RELAXED, __HIP_MEMORY_SCOPE_AGENT);
}

// ---------------------------------------------------------------------------
// Transpose fp32 [R][C] -> bf16 [C][R] (K-major layouts for MFMA B-operands)
// ---------------------------------------------------------------------------
__global__ __launch_bounds__(256) void k_transpose_cvt(
    const float* __restrict__ in, unsigned short* __restrict__ out, int R, int C) {
  __shared__ float tile[64][65];
  const int tx = threadIdx.x & 63, ty = threadIdx.x >> 6;
  const int c0 = blockIdx.x * 64, r0 = blockIdx.y * 64;
#pragma unroll
  for (int i = 0; i < 16; i++) {
    int r = i * 4 + ty;
    tile[r][tx] = in[(size_t)(r0 + r) * C + c0 + tx];
  }
  __syncthreads();
#pragma unroll
  for (int i = 0; i < 16; i++) {
    int c = i * 4 + ty;
    out[(size_t)(c0 + c) * R + r0 + tx] = f2bf(tile[tx][c]);
  }
}

// ---------------------------------------------------------------------------
// bias = b_ih + b_hh ; zero flags (ws is poisoned 0xAA every launch)
// ---------------------------------------------------------------------------
__global__ __launch_bounds__(256) void k_prep(
    const float* __restrict__ bih, const float* __restrict__ bhh,
    float* __restrict__ bias, unsigned int* __restrict__ cnt) {
  int gid = blockIdx.x * 256 + threadIdx.x;
  if (gid < H_) bias[gid] = bih[gid] + bhh[gid];
  cnt[gid] = 0u;
}

// ---------------------------------------------------------------------------
// Phase 1: xw = x @ w_ih + bias  -> written into d_out's hidden_seq region
// ---------------------------------------------------------------------------
__global__ __launch_bounds__(256) void k_gemm_xw(
    const float* __restrict__ x, const unsigned short* __restrict__ wihT,
    const float* __restrict__ bias, float* __restrict__ out) {
  __shared__ __align__(16) unsigned short As[128 * 40];
  __shared__ __align__(16) unsigned short Bs[128 * 40];

  const int tid = threadIdx.x;
  const int tileM = blockIdx.x >> 3;
  const int tileN = blockIdx.x & 7;
  const int wv = tid >> 6, lane = tid & 63;
  const int row16 = lane & 15, quad = lane >> 4;
  const int m0 = (wv & 1) * 64, n0 = (wv >> 1) * 64;

  f32x4 acc[4][4];
#pragma unroll
  for (int i = 0; i < 4; i++)
#pragma unroll
    for (int j = 0; j < 4; j++) acc[i][j] = (f32x4){0.f, 0.f, 0.f, 0.f};

  const int ar = tid >> 3, ac = (tid & 7) << 2;
  const int br = tid >> 2, bc = (tid & 3) << 3;

#pragma unroll 1
  for (int kt = 0; kt < I_ / 32; kt++) {
    const int k0 = kt * 32;
#pragma unroll
    for (int i = 0; i < 4; i++) {
      int r = ar + i * 32;
      float4 v = *(const float4*)(x + (size_t)(tileM * 128 + r) * I_ + k0 + ac);
      us4v o;
      o.x = f2bf(v.x); o.y = f2bf(v.y); o.z = f2bf(v.z); o.w = f2bf(v.w);
      *(us4v*)(As + r * 40 + ac) = o;
    }
#pragma unroll
    for (int i = 0; i < 2; i++) {
      int r = br + i * 64;
      *(uint4*)(Bs + r * 40 + bc) =
          *(const uint4*)(wihT + (size_t)(tileN * 128 + r) * I_ + k0 + bc);
    }
    __syncthreads();

    bf16x8 af[4], bfr[4];
#pragma unroll
    for (int mt = 0; mt < 4; mt++)
      af[mt] = *(const bf16x8*)(As + (m0 + mt * 16 + row16) * 40 + quad * 8);
#pragma unroll
    for (int nt = 0; nt < 4; nt++)
      bfr[nt] = *(const bf16x8*)(Bs + (n0 + nt * 16 + row16) * 40 + quad * 8);
#pragma unroll
    for (int mt = 0; mt < 4; mt++)
#pragma unroll
      for (int nt = 0; nt < 4; nt++)
        acc[mt][nt] = __builtin_amdgcn_mfma_f32_16x16x32_bf16(
            af[mt], bfr[nt], acc[mt][nt], 0, 0, 0);
    __syncthreads();
  }

#pragma unroll
  for (int mt = 0; mt < 4; mt++)
#pragma unroll
    for (int nt = 0; nt < 4; nt++) {
      int gc = tileN * 128 + n0 + nt * 16 + row16;
      float bv = bias[gc];
#pragma unroll
      for (int r = 0; r < 4; r++) {
        int gr = tileM * 128 + m0 + mt * 16 + quad * 4 + r;
        out[(size_t)gr * H_ + gc] = acc[mt][nt][r] + bv;
      }
    }
}

// ---------------------------------------------------------------------------
// Phase 2: persistent recurrence, fence-free message passing.
// 64 blocks = 4 groups(16 batches) x 16 column-chunks(64 cols).
// w_hh column fragments stationary in registers (128 VGPRs/lane).
// h exchange: row-major bf16 [slot][64 rows][1024 cols] in L3 via relaxed
// agent-scope atomics.  ONE SLOT = 64*256 = 16384 ull (r3 bug: used 8192,
// slot 1 aliased rows 32-63 of slot 0 -> groups 2/3 corrupted).
// Per-wave flags; NO __syncthreads in the loop.  sched_barrier(0) pins:
// all 64 h-loads issue before the MFMAs (one L3 round-trip), and
// h-stores -> waitcnt(0) -> flag ordering.  Hidden-seq stores + next xw
// prefetch happen AFTER the flag post (off the critical path).
// ---------------------------------------------------------------------------
#define SLOT_ (16384)

__global__ __launch_bounds__(256, 1) void k_scan(
    const unsigned short* __restrict__ whhT,
    unsigned short* __restrict__ hbuf, unsigned int* __restrict__ cnt,
    float* __restrict__ out) {
  const int bid = blockIdx.x;
  const int g = bid >> 4, j = bid & 15;
  const int tid = threadIdx.x;
  const int wv = tid >> 6, lane = tid & 63;
  const int row = lane & 15, quad = lane >> 4;
  const int bsl = g * 16;                       // batch slice base
  const int mycol = j * 64 + wv * 16 + row;     // this lane's output column

  ull* hb = (ull*)hbuf;                         // 2 slots x 64 x 1024 bf16
  unsigned int* flg = cnt + g * 64;

  // stationary B-operand: whh[k][mycol], K-major, 32 chunks of K=32
  bf16x8 wfrag[32];
  {
    const unsigned short* wp = whhT + (size_t)mycol * H_ + quad * 8;
#pragma unroll
    for (int kk = 0; kk < 32; kk++)
      wfrag[kk] = *(const bf16x8*)(wp + kk * 32);
  }

  // producer store base (ull units): row (bsl+quad*4+r)*256 + col0/4
  const int pst = (bsl) * 256 + ((j * 64 + wv * 16 + (row & ~3)) >> 2);
  // consumer load base (ull units): row (bsl+row)*256 + quad*2, +kb*8
  const int cld = (bsl + row) * 256 + quad * 2;

  // xw prefetch for t=0
  float xwv[4];
  size_t oi[4];
#pragma unroll
  for (int r = 0; r < 4; r++) {
    int b = bsl + quad * 4 + r;
    oi[r] = ((size_t)b * T_) * H_ + mycol;
    xwv[r] = out[oi[r]];
  }

  for (int t = 0; t < T_; ++t) {
    f32x4 acc[4];
#pragma unroll
    for (int c = 0; c < 4; c++) acc[c] = (f32x4){0.f, 0.f, 0.f, 0.f};

    if (t > 0) {
      // per-wave spin: all 64 flags of this group must reach t
      const unsigned int tgt = (unsigned int)t;
      while (true) {
        unsigned int f = ld_ag32(flg + lane);
        if (__ballot(f >= tgt) == ~0ull) break;
      }
      // issue ALL 64 h loads back-to-back; sched_barrier stops the compiler
      // from sinking them into the MFMA loop (one L3 round-trip, not 32)
      const ull* base = hb + ((t - 1) & 1) * SLOT_ + cld;
      ull va[64];
#pragma unroll
      for (int kb = 0; kb < 32; kb++) {
        va[2 * kb]     = ld_ag64(base + kb * 8);
        va[2 * kb + 1] = ld_ag64(base + kb * 8 + 1);
      }
      __builtin_amdgcn_sched_barrier(0);
#pragma unroll
      for (int kb = 0; kb < 32; kb++) {
        u64x2 p; p.x = va[2 * kb]; p.y = va[2 * kb + 1];
        bf16x8 a = __builtin_bit_cast(bf16x8, p);
        acc[kb & 3] = __builtin_amdgcn_mfma_f32_16x16x32_bf16(
            a, wfrag[kb], acc[kb & 3], 0, 0, 0);
      }
    }
    f32x4 accf = (acc[0] + acc[1]) + (acc[2] + acc[3]);

    // h = tanh(acc + xw); publish bf16 h packed to 8B via shfl
    float hv[4];
    ull* pbase = hb + (t & 1) * SLOT_ + pst;
#pragma unroll
    for (int r = 0; r < 4; r++) {
      float h = fast_tanh(accf[r] + xwv[r]);
      hv[r] = h;
      unsigned int myu = (unsigned int)f2bf(h);
      unsigned int pr  = __shfl_xor(myu, 1);
      unsigned int pair = (lane & 1) ? 0u : (myu | (pr << 16));
      unsigned int hi  = __shfl_xor(pair, 2);
      if ((lane & 3) == 0) {
        ull q = (ull)pair | ((ull)hi << 32);
        st_ag64(pbase + (quad * 4 + r) * 256, q);
      }
    }
    // order: h stores acked at L3, THEN flag. sched_barriers pin the order.
    __builtin_amdgcn_sched_barrier(0);
    __builtin_amdgcn_s_waitcnt(0);
    __builtin_amdgcn_sched_barrier(0);
    if (lane == 0) st_ag32(&flg[j * 4 + wv], (unsigned int)(t + 1));
    __builtin_amdgcn_sched_barrier(0);

    // off-critical-path: hidden_seq stores, h_T tail, next xw prefetch
#pragma unroll
    for (int r = 0; r < 4; r++) {
      out[oi[r]] = hv[r];
      if (t == T_ - 1) {
        int b = bsl + quad * 4 + r;
        out[(size_t)B_ * T_ * H_ + (size_t)b * H_ + mycol] = hv[r];
      }
    }
    if (t + 1 < T_) {
#pragma unroll
      for (int r = 0; r < 4; r++) {
        oi[r] += H_;                 // (b*T + t+1)*H + mycol
        xwv[r] = out[oi[r]];
      }
    }
  }
}

// ---------------------------------------------------------------------------
extern "C" void kernel_launch(void* const* d_in, const int* in_sizes, int n_in,
                              void* d_out, int out_size, void* d_ws, size_t ws_size,
                              hipStream_t stream) {
  const float* x    = (const float*)d_in[0];
  const float* w_ih = (const float*)d_in[1];
  const float* w_hh = (const float*)d_in[2];
  const float* b_ih = (const float*)d_in[3];
  const float* b_hh = (const float*)d_in[4];
  float* out = (float*)d_out;

  char* ws = (char*)d_ws;
  unsigned short* whhT = (unsigned short*)(ws);                       // 2 MB
  unsigned short* wihT = (unsigned short*)(ws + (2u << 20));          // 1 MB
  float*          bias = (float*)(ws + (3u << 20));                   // 4 KB
  unsigned int*   cnt  = (unsigned int*)(ws + (3u << 20) + 4096);     // 8 KB
  unsigned short* hbuf = (unsigned short*)(ws + (3u << 20) + 4096 + 8192); // 256 KB

  hipLaunchKernelGGL(k_transpose_cvt, dim3(H_ / 64, H_ / 64), dim3(256), 0, stream,
                     w_hh, whhT, H_, H_);
  hipLaunchKernelGGL(k_transpose_cvt, dim3(H_ / 64, I_ / 64), dim3(256), 0, stream,
                     w_ih, wihT, I_, H_);
  hipLaunchKernelGGL(k_prep, dim3(8), dim3(256), 0, stream, b_ih, b_hh, bias, cnt);
  hipLaunchKernelGGL(k_gemm_xw, dim3((B_ * T_ / 128) * (H_ / 128)), dim3(256), 0,
                     stream, x, wihT, bias, out);
  hipLaunchKernelGGL(k_scan, dim3(64), dim3(256), 0, stream, whhT, hbuf, cnt, out);
}

// Round 5
// 2098.214 us; speedup vs baseline: 2.7642x; 2.7642x over previous
//
#include <hip/hip_runtime.h>
#include <cstdint>
#include <cstddef>

#define B_  64
#define T_  512
#define I_  512
#define H_  1024

typedef float  f32x4  __attribute__((ext_vector_type(4)));
typedef __bf16 bf16x8 __attribute__((ext_vector_type(8)));
typedef unsigned short us4v __attribute__((ext_vector_type(4)));
typedef unsigned int  u32x4 __attribute__((ext_vector_type(4)));
typedef unsigned long long ull;

__device__ __forceinline__ unsigned short f2bf(float f) {
  unsigned int u = __float_as_uint(f);
  u = (u + 0x7fffu + ((u >> 16) & 1u)) >> 16;   // round-to-nearest-even
  return (unsigned short)u;
}

__device__ __forceinline__ float fast_tanh(float x) {
  x = fminf(10.f, fmaxf(-10.f, x));
  float e = __expf(2.f * x);
  return (e - 1.f) * __builtin_amdgcn_rcpf(e + 1.f);
}

// Relaxed agent-scope atomics: coherent at the device coherence point,
// no cache-maintenance instructions, bypass stale per-XCD caching.
__device__ __forceinline__ void st_ag64(ull* p, ull v) {
  __hip_atomic_store(p, v, __ATOMIC_RELAXED, __HIP_MEMORY_SCOPE_AGENT);
}
__device__ __forceinline__ ull ld_ag64(const ull* p) {
  return __hip_atomic_load(p, __ATOMIC_RELAXED, __HIP_MEMORY_SCOPE_AGENT);
}

// ---------------------------------------------------------------------------
// Transpose fp32 [R][C] -> bf16 [C][R] (K-major layouts for MFMA B-operands)
// ---------------------------------------------------------------------------
__global__ __launch_bounds__(256) void k_transpose_cvt(
    const float* __restrict__ in, unsigned short* __restrict__ out, int R, int C) {
  __shared__ float tile[64][65];
  const int tx = threadIdx.x & 63, ty = threadIdx.x >> 6;
  const int c0 = blockIdx.x * 64, r0 = blockIdx.y * 64;
#pragma unroll
  for (int i = 0; i < 16; i++) {
    int r = i * 4 + ty;
    tile[r][tx] = in[(size_t)(r0 + r) * C + c0 + tx];
  }
  __syncthreads();
#pragma unroll
  for (int i = 0; i < 16; i++) {
    int c = i * 4 + ty;
    out[(size_t)(c0 + c) * R + r0 + tx] = f2bf(tile[tx][c]);
  }
}

// ---------------------------------------------------------------------------
// bias = b_ih + b_hh  (tagged hbuf needs NO init: 0xAA poison is never a tag)
// ---------------------------------------------------------------------------
__global__ __launch_bounds__(256) void k_prep(
    const float* __restrict__ bih, const float* __restrict__ bhh,
    float* __restrict__ bias) {
  int gid = blockIdx.x * 256 + threadIdx.x;
  if (gid < H_) bias[gid] = bih[gid] + bhh[gid];
}

// ---------------------------------------------------------------------------
// Phase 1: xw = x @ w_ih + bias  -> written into d_out's hidden_seq region
// ---------------------------------------------------------------------------
__global__ __launch_bounds__(256) void k_gemm_xw(
    const float* __restrict__ x, const unsigned short* __restrict__ wihT,
    const float* __restrict__ bias, float* __restrict__ out) {
  __shared__ __align__(16) unsigned short As[128 * 40];
  __shared__ __align__(16) unsigned short Bs[128 * 40];

  const int tid = threadIdx.x;
  const int tileM = blockIdx.x >> 3;
  const int tileN = blockIdx.x & 7;
  const int wv = tid >> 6, lane = tid & 63;
  const int row16 = lane & 15, quad = lane >> 4;
  const int m0 = (wv & 1) * 64, n0 = (wv >> 1) * 64;

  f32x4 acc[4][4];
#pragma unroll
  for (int i = 0; i < 4; i++)
#pragma unroll
    for (int j = 0; j < 4; j++) acc[i][j] = (f32x4){0.f, 0.f, 0.f, 0.f};

  const int ar = tid >> 3, ac = (tid & 7) << 2;
  const int br = tid >> 2, bc = (tid & 3) << 3;

#pragma unroll 1
  for (int kt = 0; kt < I_ / 32; kt++) {
    const int k0 = kt * 32;
#pragma unroll
    for (int i = 0; i < 4; i++) {
      int r = ar + i * 32;
      float4 v = *(const float4*)(x + (size_t)(tileM * 128 + r) * I_ + k0 + ac);
      us4v o;
      o.x = f2bf(v.x); o.y = f2bf(v.y); o.z = f2bf(v.z); o.w = f2bf(v.w);
      *(us4v*)(As + r * 40 + ac) = o;
    }
#pragma unroll
    for (int i = 0; i < 2; i++) {
      int r = br + i * 64;
      *(uint4*)(Bs + r * 40 + bc) =
          *(const uint4*)(wihT + (size_t)(tileN * 128 + r) * I_ + k0 + bc);
    }
    __syncthreads();

    bf16x8 af[4], bfr[4];
#pragma unroll
    for (int mt = 0; mt < 4; mt++)
      af[mt] = *(const bf16x8*)(As + (m0 + mt * 16 + row16) * 40 + quad * 8);
#pragma unroll
    for (int nt = 0; nt < 4; nt++)
      bfr[nt] = *(const bf16x8*)(Bs + (n0 + nt * 16 + row16) * 40 + quad * 8);
#pragma unroll
    for (int mt = 0; mt < 4; mt++)
#pragma unroll
      for (int nt = 0; nt < 4; nt++)
        acc[mt][nt] = __builtin_amdgcn_mfma_f32_16x16x32_bf16(
            af[mt], bfr[nt], acc[mt][nt], 0, 0, 0);
    __syncthreads();
  }

#pragma unroll
  for (int mt = 0; mt < 4; mt++)
#pragma unroll
    for (int nt = 0; nt < 4; nt++) {
      int gc = tileN * 128 + n0 + nt * 16 + row16;
      float bv = bias[gc];
#pragma unroll
      for (int r = 0; r < 4; r++) {
        int gr = tileM * 128 + m0 + mt * 16 + quad * 4 + r;
        out[(size_t)gr * H_ + gc] = acc[mt][nt][r] + bv;
      }
    }
}

// ---------------------------------------------------------------------------
// Phase 2: persistent recurrence with DATA-IS-FLAG message passing.
// 64 blocks = 4 groups(16 batches) x 16 column-chunks(64 cols).
// w_hh column fragments stationary in registers (128 VGPRs/lane).
//
// h exchange: tagged 8B words { hi32 = tag = t+1, lo32 = 2 x bf16 }.
// Single-copy atomicity of the 8B store means tag+payload arrive together:
// NO waitcnt, NO flag array, NO separate flag round trip. Consumers poll
// the data words until all tags match. 0xAA ws poison is never a valid tag.
// Ping-pong parity slots; safety: producer can only reach step t+2 (slot
// reuse) after consuming everyone's t+1 data, which implies everyone
// consumed t's data.
//
// Per block, the 256 threads cooperatively load the group's tagged h
// (8192 words, coalesced, per-thread stale retry), broadcast payloads via
// double-buffered LDS (row pad +4 words -> 2-way-free banks), ONE
// __syncthreads, then each wave reads A-fragments with ds_read_b128.
// hidden_seq stores + next-xw prefetch sit after the publish (off-path).
// ---------------------------------------------------------------------------
__global__ __launch_bounds__(256, 1) void k_scan(
    const unsigned short* __restrict__ whhT,
    unsigned short* __restrict__ hbuf,
    float* __restrict__ out) {
  const int bid = blockIdx.x;
  const int g = bid >> 4, j = bid & 15;
  const int tid = threadIdx.x;
  const int wv = tid >> 6, lane = tid & 63;
  const int row = lane & 15, quad = lane >> 4;
  const int bsl = g * 16;                       // batch slice base
  const int mycol = j * 64 + wv * 16 + row;     // this lane's output column

  // tagged h: [group(4)][parity(2)][8192 words] ull
  ull* hb = (ull*)hbuf;
  ull* gbase = hb + g * 16384;

  // LDS payload broadcast: 2 buffers x 16 rows x 516 u32 (pad 512->516)
  __shared__ __align__(16) unsigned int ldsb[2 * 16 * 516];

  // stationary B-operand: whh[k][mycol], K-major, 32 chunks of K=32
  bf16x8 wfrag[32];
  {
    const unsigned short* wp = whhT + (size_t)mycol * H_ + quad * 8;
#pragma unroll
    for (int kk = 0; kk < 32; kk++)
      wfrag[kk] = *(const bf16x8*)(wp + kk * 32);
  }

  // xw prefetch for t=0
  float xwv[4];
  size_t oi[4];
#pragma unroll
  for (int r = 0; r < 4; r++) {
    int b = bsl + quad * 4 + r;
    oi[r] = ((size_t)b * T_) * H_ + mycol;
    xwv[r] = out[oi[r]];
  }

  for (int t = 0; t < T_; ++t) {
    f32x4 acc[4];
#pragma unroll
    for (int c = 0; c < 4; c++) acc[c] = (f32x4){0.f, 0.f, 0.f, 0.f};

    if (t > 0) {
      // --- cooperative tagged load: thread owns words { i*256 + tid } ---
      const ull* src = gbase + ((t - 1) & 1) * 8192;
      const unsigned int expect = (unsigned int)t;
      unsigned int pay[32];
      bool ok;
      do {
        ok = true;
#pragma unroll
        for (int i = 0; i < 32; i++) {
          ull q = ld_ag64(src + i * 256 + tid);
          pay[i] = (unsigned int)q;
          ok &= ((unsigned int)(q >> 32) == expect);
        }
      } while (__builtin_expect(!ok, 0));

      // --- LDS broadcast: word w=i*256+tid -> lds[(w>>9)*516 + (w&511)] ---
      unsigned int* lw = ldsb + (t & 1) * (16 * 516);
#pragma unroll
      for (int i = 0; i < 32; i++)
        lw[(i >> 1) * 516 + (i & 1) * 256 + tid] = pay[i];
      __syncthreads();

      // --- MFMA from LDS A-fragments ---
      const unsigned int* ap = lw + row * 516 + quad * 4;
#pragma unroll
      for (int kb = 0; kb < 32; kb++) {
        u32x4 w = *(const u32x4*)(ap + kb * 16);     // ds_read_b128
        bf16x8 a = __builtin_bit_cast(bf16x8, w);
        acc[kb & 3] = __builtin_amdgcn_mfma_f32_16x16x32_bf16(
            a, wfrag[kb], acc[kb & 3], 0, 0, 0);
      }
    }
    f32x4 accf = (acc[0] + acc[1]) + (acc[2] + acc[3]);

    // h = tanh(acc + xw); publish tagged bf16 pairs (8B, tag rides along)
    float hv[4];
    ull* dst = gbase + (t & 1) * 8192;
    const ull tagbits = ((ull)(unsigned int)(t + 1)) << 32;
#pragma unroll
    for (int r = 0; r < 4; r++) {
      float h = fast_tanh(accf[r] + xwv[r]);
      hv[r] = h;
      unsigned int myu = (unsigned int)f2bf(h);
      unsigned int pr  = __shfl_xor(myu, 1);
      unsigned int pair = myu | (pr << 16);          // valid on even lanes
      if ((lane & 1) == 0) {
        int b = quad * 4 + r;
        st_ag64(dst + b * 512 + (mycol >> 1), tagbits | (ull)pair);
      }
    }
    __builtin_amdgcn_sched_barrier(0);   // publish issues before out[] I/O

    // off-critical-path: hidden_seq stores, h_T tail, next xw prefetch
#pragma unroll
    for (int r = 0; r < 4; r++) {
      out[oi[r]] = hv[r];
      if (t == T_ - 1) {
        int b = bsl + quad * 4 + r;
        out[(size_t)B_ * T_ * H_ + (size_t)b * H_ + mycol] = hv[r];
      }
    }
    if (t + 1 < T_) {
#pragma unroll
      for (int r = 0; r < 4; r++) {
        oi[r] += H_;                 // (b*T + t+1)*H + mycol
        xwv[r] = out[oi[r]];
      }
    }
  }
}

// ---------------------------------------------------------------------------
extern "C" void kernel_launch(void* const* d_in, const int* in_sizes, int n_in,
                              void* d_out, int out_size, void* d_ws, size_t ws_size,
                              hipStream_t stream) {
  const float* x    = (const float*)d_in[0];
  const float* w_ih = (const float*)d_in[1];
  const float* w_hh = (const float*)d_in[2];
  const float* b_ih = (const float*)d_in[3];
  const float* b_hh = (const float*)d_in[4];
  float* out = (float*)d_out;

  char* ws = (char*)d_ws;
  unsigned short* whhT = (unsigned short*)(ws);                       // 2 MB
  unsigned short* wihT = (unsigned short*)(ws + (2u << 20));          // 1 MB
  float*          bias = (float*)(ws + (3u << 20));                   // 4 KB
  unsigned short* hbuf = (unsigned short*)(ws + (3u << 20) + 4096);   // 512 KB tagged

  hipLaunchKernelGGL(k_transpose_cvt, dim3(H_ / 64, H_ / 64), dim3(256), 0, stream,
                     w_hh, whhT, H_, H_);
  hipLaunchKernelGGL(k_transpose_cvt, dim3(H_ / 64, I_ / 64), dim3(256), 0, stream,
                     w_ih, wihT, I_, H_);
  hipLaunchKernelGGL(k_prep, dim3(4), dim3(256), 0, stream, b_ih, b_hh, bias);
  hipLaunchKernelGGL(k_gemm_xw, dim3((B_ * T_ / 128) * (H_ / 128)), dim3(256), 0,
                     stream, x, wihT, bias, out);
  hipLaunchKernelGGL(k_scan, dim3(64), dim3(256), 0, stream, whhT, hbuf, out);
}